// Round 10
// baseline (346.666 us; speedup 1.0000x reference)
//
#include <hip/hip_runtime.h>
#include <stdint.h>

typedef uint16_t u16;
typedef __attribute__((ext_vector_type(8))) short short8;
typedef __attribute__((ext_vector_type(4))) float f32x4;
typedef __attribute__((ext_vector_type(16))) float f32x16;

#define MFMA16(a, b, c) __builtin_amdgcn_mfma_f32_16x16x32_bf16((a), (b), (c), 0, 0, 0)
#define MFMA32(a, b, c) __builtin_amdgcn_mfma_f32_32x32x16_bf16((a), (b), (c), 0, 0, 0)
#define AS1 __attribute__((address_space(1)))
#define AS3 __attribute__((address_space(3)))

__device__ __forceinline__ void gld_lds16(const u16* g, u16* l) {
  __builtin_amdgcn_global_load_lds((const AS1 void*)g, (AS3 void*)l, 16, 0, 0);
}

__device__ __forceinline__ u16 f2bf(float f) {
  uint32_t u = __float_as_uint(f);
  u += 0x7fffu + ((u >> 16) & 1u);
  return (u16)(u >> 16);
}

// ---------------- fused fp32 -> bf16, 32B/thread (x, w_qkv, w_out) ----------
__global__ __launch_bounds__(256) void cvt_all(const float* __restrict__ x,
                                               const float* __restrict__ wqkv,
                                               const float* __restrict__ wout,
                                               u16* __restrict__ xb,
                                               u16* __restrict__ wqkvb,
                                               u16* __restrict__ woutb) {
  const int n1 = 8388608 / 8, n2 = 12582912 / 8;  // x, w_qkv float8 counts
  int i = blockIdx.x * 256 + threadIdx.x;
  const float* src;
  u16* dst;
  int j;
  if (i < n1) {
    src = x; dst = xb; j = i;
  } else if (i < n1 + n2) {
    src = wqkv; dst = wqkvb; j = i - n1;
  } else {
    src = wout; dst = woutb; j = i - n1 - n2;
  }
  float4 v0 = ((const float4*)src)[j * 2];
  float4 v1 = ((const float4*)src)[j * 2 + 1];
  uint4 o;
  o.x = (uint32_t)f2bf(v0.x) | ((uint32_t)f2bf(v0.y) << 16);
  o.y = (uint32_t)f2bf(v0.z) | ((uint32_t)f2bf(v0.w) << 16);
  o.z = (uint32_t)f2bf(v1.x) | ((uint32_t)f2bf(v1.y) << 16);
  o.w = (uint32_t)f2bf(v1.z) | ((uint32_t)f2bf(v1.w) << 16);
  ((uint4*)dst)[j] = o;
}

// ---------------- asm-fenced barriers (compiler may NOT reorder memory ops
// across these; the vmcnt ledger depends on issue order) ----------------------
template <int N>
__device__ __forceinline__ void bar_vm() {
  asm volatile("s_waitcnt vmcnt(%0)\n\ts_barrier" ::"n"(N) : "memory");
}
__device__ __forceinline__ void bar_fence() {
  asm volatile("s_barrier" ::: "memory");
}

// ============================================================================
// 8-phase 256x256 GEMM (QK-proj).  C[256,256] tile = A[256,K]*B[256,K]^T.
// R10: DEEP prefetch ledger.  R9's schedule issued Ae(t+1) only 2 phases
// (~600cyc) before its deadline -> per-tile HBM-latency stall (MfmaUtil 42%).
// B slots are free a full tile earlier (B slot[(t+2)&1] last read at t q0),
// so stage per tile t:  q0:Ae(t+1)  q1:Ao(t+1)  q2:B0(t+2)  q3:B1(t+2)
// -> every half has >=4 phases (~1200cyc) of slack.
// Ledger (2 loads/batch; invariant entering tile t: {Ao(t),B0(t+1),B1(t+1)}):
//   q0-end: plain fenced barrier          (outstanding 4 batches)
//   q1-end: vmcnt(8)  requires Ao(t)      (5 batches -> keep 4)
//   q2-end: plain fenced barrier          (5 batches)
//   q3-end: vmcnt(6)  requires Ae,B0,B1(t+1)  (6 batches -> keep 3)
// Tails: t=NT-2: q3-end vmcnt(2); t=NT-1: q1-end vmcnt(0), no q3 barrier.
// WAR safety: every stage overwrites a region whose last reader passed >=2
// fenced barriers earlier (checked per-region).  All barriers asm-fenced.
// Q columns (nt<8) pre-scaled by HD^-0.5*log2(e) so flash softmax = exp2(S).
// ============================================================================
__global__ __launch_bounds__(512, 2) void proj8_gemm(const u16* __restrict__ xb,
                                                     const u16* __restrict__ wqkvb,
                                                     u16* __restrict__ qkb) {
  constexpr int ASZ = 256 * 64;  // u16 per slot
  constexpr int NT = 32;         // 2048 / BK=64
  __shared__ u16 sm[4 * ASZ];    // [A0][A1][B0][B1] = 128 KiB

  int bx = blockIdx.x;
  bx = (bx & 7) * 32 + (bx >> 3);  // 256 = 8 XCD chunks of 32
  const int mt = bx >> 4, nt = bx & 15;
  const u16* Ab = xb + (size_t)mt * 256 * 2048;
  const u16* Bb = wqkvb + (size_t)nt * 256 * 2048;
  u16* C = qkb + (size_t)mt * 256 * 4096 + nt * 256;

  const int tid = threadIdx.x, lane = tid & 63, w = tid >> 6;
  const int wm = w >> 2, wn = w & 3;
  const int lo = lane & 15, q4 = lane >> 4;

  f32x4 acc[8][4];
  const f32x4 fzero = {0.f, 0.f, 0.f, 0.f};
#pragma unroll
  for (int i = 0; i < 8; ++i)
#pragma unroll
    for (int j = 0; j < 4; ++j) acc[i][j] = fzero;

  // stage one 16 KiB half of K-tile tau.  h: 0=B rows 0-127, 1=B rows 128-255,
  // 2=A rows {0-63,128-191} (Ae), 3=A rows {64-127,192-255} (Ao).
  auto stage_half = [&](int tau, int h) {
    const int slot = tau & 1;
    const int k0 = tau * 64;
    const u16* G = (h < 2) ? Bb : Ab;
    u16* L = sm + (h < 2 ? 2 * ASZ : 0) + slot * ASZ;
#pragma unroll
    for (int s = 0; s < 2; ++s) {
      const int c = tid + s * 512;        // 0..1023 chunk-in-half
      const int hr = c >> 3, pc = c & 7;  // hr 0..127
      const int r = (h < 2) ? (h * 128 + hr)
                            : ((hr & 63) + ((hr >> 6) << 7) + ((h & 1) << 6));
      const int c4 = pc ^ (r & 7);  // pre-swizzled global chunk
      gld_lds16(G + (size_t)r * 2048 + k0 + c4 * 8, L + r * 64 + pc * 8);
    }
  };

  // prologue: tile 0 fully + B halves of tile 1 (emulates steady state)
  stage_half(0, 0);
  stage_half(0, 1);
  stage_half(0, 2);
  stage_half(0, 3);
  stage_half(1, 0);
  stage_half(1, 1);
  bar_vm<6>();  // B0,B1,Ae(0) landed; {Ao(0),B0(1),B1(1)} in flight

  for (int tau = 0; tau < NT; ++tau) {
    const u16* As = sm + (tau & 1) * ASZ;
    const u16* Bs = sm + 2 * ASZ + (tau & 1) * ASZ;
    short8 bf[8];
#pragma unroll
    for (int q = 0; q < 4; ++q) {
      // deep-prefetch schedule
      if (q == 0) {
        if (tau + 1 < NT) stage_half(tau + 1, 2);  // Ae(t+1)
      } else if (q == 1) {
        if (tau + 1 < NT) stage_half(tau + 1, 3);  // Ao(t+1)
      } else if (q == 2) {
        if (tau + 2 < NT) stage_half(tau + 2, 0);  // B0(t+2)
      } else {
        if (tau + 2 < NT) stage_half(tau + 2, 1);  // B1(t+2)
      }
      if (q == 0) {
#pragma unroll
        for (int j = 0; j < 4; ++j)
#pragma unroll
          for (int kk = 0; kk < 2; ++kk) {
            const int r = wn * 64 + j * 16 + lo;
            bf[j * 2 + kk] =
                *(const short8*)(Bs + r * 64 + (((kk * 4 + q4) ^ (r & 7)) * 8));
          }
      }
      short8 af[2][2];
#pragma unroll
      for (int i = 0; i < 2; ++i)
#pragma unroll
        for (int kk = 0; kk < 2; ++kk) {
          const int r = wm * 128 + q * 32 + i * 16 + lo;
          af[i][kk] =
              *(const short8*)(As + r * 64 + (((kk * 4 + q4) ^ (r & 7)) * 8));
        }
      bar_fence();  // mid-phase: issue work done, enter MFMA (asm-fenced)
      __builtin_amdgcn_s_setprio(1);
#pragma unroll
      for (int i = 0; i < 2; ++i)
#pragma unroll
        for (int j = 0; j < 4; ++j)
#pragma unroll
          for (int kk = 0; kk < 2; ++kk)
            acc[q * 2 + i][j] = MFMA16(af[i][kk], bf[j * 2 + kk], acc[q * 2 + i][j]);
      __builtin_amdgcn_s_setprio(0);
      // phase boundaries (ledger above)
      if (q == 1) {
        if (tau < NT - 1) bar_vm<8>();
        else bar_vm<0>();
      } else if (q == 3) {
        if (tau < NT - 2) bar_vm<6>();
        else if (tau == NT - 2) bar_vm<2>();
        // tau == NT-1: exit, no barrier
      } else {
        bar_fence();
      }
    }
  }

  // epilogue: per-wave 128x64 at (wm*128, wn*64); scale Q (nt<8) by cexp
  const float sc =
      (nt < 8) ? (0.08838834764831843f * 1.4426950408889634f) : 1.0f;
#pragma unroll
  for (int i = 0; i < 8; ++i)
#pragma unroll
    for (int j = 0; j < 4; ++j) {
      const int col = wn * 64 + j * 16 + lo;
#pragma unroll
      for (int e = 0; e < 4; ++e) {
        const int row = wm * 128 + i * 16 + q4 * 4 + e;
        C[(size_t)row * 4096 + col] = f2bf(acc[i][j][e] * sc);
      }
    }
}

// ---------------- GEMM core: cyclic-3, counted vmcnt, superrow swizzle ------
// (R2-verified, 0 bank conflicts.)  C[BM,128] += A[BM,K]*B[128,K]^T, BK=32.
template <int MFR>  // 8 => BM=256, 4 => BM=128
__device__ __forceinline__ void gemm_core3(const u16* __restrict__ Ab,
                                           const u16* __restrict__ Bb,
                                           u16* sm, int tid,
                                           f32x4 acc[MFR][4]) {
  constexpr int AROWS = MFR * 32;
  constexpr int ASZ = AROWS * 32;
  constexpr int BSZ = 128 * 32;
  constexpr int BUF = ASZ + BSZ;
  constexpr int NT = 64;
  constexpr int ALD = AROWS / 64;
  constexpr int VN = ALD + 2;

  const int lane = tid & 63, w = tid >> 6;
  const int wr = w >> 1, wc = w & 1;
  const int lo = lane & 15, q4 = lane >> 4;
  const int pcl = (((lo & 1) << 2) | q4) ^ ((lo >> 1) & 7);
  const int loff = (lo >> 1) * 64 + pcl * 8;

  auto stage = [&](int g) {
    u16* As = sm + (g % 3) * BUF;
    u16* Bs = As + ASZ;
    const int k0 = g * 32;
#pragma unroll
    for (int s = 0; s < ALD; ++s) {
      const int c = tid + s * 256;
      const int sr = c >> 3, pc = c & 7;
      const int t = pc ^ (sr & 7);
      const int r = sr * 2 + (t >> 2), c4 = t & 3;
      gld_lds16(Ab + (size_t)r * 2048 + k0 + c4 * 8, As + c * 8);
    }
#pragma unroll
    for (int s = 0; s < 2; ++s) {
      const int c = tid + s * 256;
      const int sr = c >> 3, pc = c & 7;
      const int t = pc ^ (sr & 7);
      const int r = sr * 2 + (t >> 2), c4 = t & 3;
      gld_lds16(Bb + (size_t)r * 2048 + k0 + c4 * 8, Bs + c * 8);
    }
  };

  stage(0);
  stage(1);
  bar_vm<VN>();

  for (int g = 0; g < NT; ++g) {
    const u16* As = sm + (g % 3) * BUF;
    const u16* Bs = As + ASZ;
    if (g + 2 < NT) stage(g + 2);
    short8 af[MFR], bf[4];
#pragma unroll
    for (int i = 0; i < MFR; ++i)
      af[i] = *(const short8*)(As + (wr * (MFR * 16) + i * 16) * 32 + loff);
#pragma unroll
    for (int j = 0; j < 4; ++j)
      bf[j] = *(const short8*)(Bs + (wc * 64 + j * 16) * 32 + loff);
    __builtin_amdgcn_s_setprio(1);
#pragma unroll
    for (int i = 0; i < MFR; ++i)
#pragma unroll
      for (int j = 0; j < 4; ++j) acc[i][j] = MFMA16(af[i], bf[j], acc[i][j]);
    __builtin_amdgcn_s_setprio(0);
    if (g + 1 < NT) {
      if (g + 2 < NT) {
        bar_vm<VN>();
      } else {
        bar_vm<0>();
      }
    }
  }
}

// ---------------- V^T projection: vt[d, b*t] = Wv * x^T ----------------
// 512 blocks of 128x128 (MFR=4), 48 KiB -> 2 blocks/CU, one full round.
__global__ __launch_bounds__(256, 2) void vproj_gemm(const u16* __restrict__ wqkvb,
                                                     const u16* __restrict__ xb,
                                                     u16* __restrict__ vtb) {
  __shared__ u16 sm[3 * (128 * 32 + 128 * 32)];  // 48 KiB
  int bx = blockIdx.x;
  bx = (bx & 7) * 64 + (bx >> 3);  // 512 = 8 XCD chunks of 64
  const int tid = threadIdx.x;
  const int mt = bx >> 5, nt = bx & 31;  // M=2048/128=16, N=4096/128=32
  const u16* Ab = wqkvb + (size_t)(4096 + mt * 128) * 2048;
  const u16* Bb = xb + (size_t)nt * 128 * 2048;
  u16* C = vtb + (size_t)mt * 128 * 4096 + nt * 128;
  f32x4 acc[4][4];
  const f32x4 fzero = {0.f, 0.f, 0.f, 0.f};
#pragma unroll
  for (int i = 0; i < 4; ++i)
#pragma unroll
    for (int j = 0; j < 4; ++j) acc[i][j] = fzero;

  gemm_core3<4>(Ab, Bb, sm, tid, acc);

  const int lane = tid & 63, w = tid >> 6;
  const int wr = w >> 1, wc = w & 1;
  const int lo = lane & 15, q4 = lane >> 4;
#pragma unroll
  for (int i = 0; i < 4; ++i)
#pragma unroll
    for (int j = 0; j < 4; ++j) {
      const int col = wc * 64 + j * 16 + lo;
#pragma unroll
      for (int e = 0; e < 4; ++e) {
        const int row = wr * 64 + i * 16 + q4 * 4 + e;
        C[(size_t)row * 4096 + col] = f2bf(acc[i][j][e]);
      }
    }
}

// ---------------- out-proj GEMM: out = attn * Wout^T + bias (f32) ----------
// 512 blocks of 128x128 (MFR=4), 48 KiB -> 2 blocks/CU, one full round.
__global__ __launch_bounds__(256, 2) void out_gemm(const u16* __restrict__ A,
                                                   const u16* __restrict__ B,
                                                   float* __restrict__ Cf,
                                                   const float* __restrict__ bias) {
  __shared__ u16 sm[3 * (128 * 32 + 128 * 32)];  // 48 KiB
  int bx = blockIdx.x;
  bx = (bx & 7) * 64 + (bx >> 3);  // 512 = 8 XCD chunks of 64
  const int tid = threadIdx.x;
  const int mt = bx >> 4, nt = bx & 15;  // M=4096/128=32, N=2048/128=16
  const u16* Ab = A + (size_t)mt * 128 * 2048;
  const u16* Bb = B + (size_t)nt * 128 * 2048;
  f32x4 acc[4][4];
  const f32x4 fzero = {0.f, 0.f, 0.f, 0.f};
#pragma unroll
  for (int i = 0; i < 4; ++i)
#pragma unroll
    for (int j = 0; j < 4; ++j) acc[i][j] = fzero;

  gemm_core3<4>(Ab, Bb, sm, tid, acc);

  const int lane = tid & 63, w = tid >> 6;
  const int wr = w >> 1, wc = w & 1;
  const int lo = lane & 15, q4 = lane >> 4;
#pragma unroll
  for (int i = 0; i < 4; ++i)
#pragma unroll
    for (int j = 0; j < 4; ++j) {
      const int col = nt * 128 + wc * 64 + j * 16 + lo;
      const float bv = bias[col];
#pragma unroll
      for (int e = 0; e < 4; ++e) {
        const int row = mt * 128 + wr * 64 + i * 16 + q4 * 4 + e;
        Cf[(size_t)row * 2048 + col] = acc[i][j][e] + bv;
      }
    }
}

// ---------------- flash attention v4: KVBLK=64, 2 blocks/CU ------------------
// (R8-verified: swapped QK^T, in-register softmax, cvt_pk+permlane pack,
// anti-paired q-tile grid, no VGPR cap; R9: setprio around MFMA clusters.)
__global__ __launch_bounds__(512) void flash_attn(const u16* __restrict__ qk,
                                                  const u16* __restrict__ vt,
                                                  u16* __restrict__ aout) {
  constexpr int T = 2048, WQK = 4096, D = 2048;
  constexpr int KT = 64 * 128;        // u16 per tile (K [64][128], V [128][64])
  __shared__ u16 smem[4 * KT + 512];  // 64 KiB KV (+1 KiB osum; epi reuse)

  const int bx = blockIdx.x;
  const int g = bx & 31;
  const int h = g & 15, b = g >> 4;
  const int qt = (bx < 256) ? (bx >> 5) : (15 - ((bx - 256) >> 5));
  const int q0 = qt * 128;
  const int tid = threadIdx.x, lane = tid & 63, w = tid >> 6;
  const int wr = w & 3, wk = w >> 2;  // 4 q-groups x 2 k-halves
  const int l31 = lane & 31, hi = lane >> 5;

  const u16* Qb = qk + (size_t)b * T * WQK + h * 128;
  const u16* Kb = Qb + 2048;
  const u16* Vtb = vt + (size_t)h * 128 * 4096 + b * 2048;
  float* fex = (float*)smem;  // epilogue scratch: [128][128] f32 + 2x128 osum

  // Q frags (B-operand): rows q0+wr*32+l31, k = kc*16+hi*8+j (pre-scaled)
  short8 qf[8];
#pragma unroll
  for (int kc = 0; kc < 8; ++kc)
    qf[kc] = *(const short8*)(Qb + (size_t)(q0 + wr * 32 + l31) * WQK +
                              kc * 16 + hi * 8);

  f32x16 o[4];
  float osum = 0.f;
#pragma unroll
  for (int dt = 0; dt < 4; ++dt)
#pragma unroll
    for (int e = 0; e < 16; ++e) o[dt][e] = 0.f;

  auto stage = [&](int kt) {
    const int kv0 = kt * 64;
    u16* Kl = smem + (kt & 1) * KT;
    u16* Vl = smem + 2 * KT + (kt & 1) * KT;
#pragma unroll
    for (int s = 0; s < 2; ++s) {
      const int c = tid + s * 512;
      {  // K: 64 rows x 16 chunks of 16B
        const int r = c >> 4, pc = c & 15;
        const int gc = pc ^ (r & 7);
        gld_lds16(Kb + (size_t)(kv0 + r) * WQK + gc * 8, Kl + c * 8);
      }
      {  // V: 128 rows x 8 chunks of 16B
        const int r = c >> 3, pc = c & 7;
        const int gc = pc ^ (r & 7);
        gld_lds16(Vtb + (size_t)r * 4096 + kv0 + gc * 8, Vl + c * 8);
      }
    }
  };

  stage(0);
  const int ktmax = 2 * qt + 1;
  for (int kt = 0; kt <= ktmax; ++kt) {
    __syncthreads();  // cur tiles landed; prev tiles' reads done
    if (kt < ktmax) stage(kt + 1);
    const u16* Ksc = smem + (kt & 1) * KT;
    const u16* Vsc = smem + 2 * KT + (kt & 1) * KT;

    // ---- S^T = K Q^T over this wave's 32-k half ----
    f32x16 s2;
#pragma unroll
    for (int e = 0; e < 16; ++e) s2[e] = 0.f;
    const int rk = wk * 32 + l31;
    __builtin_amdgcn_s_setprio(1);
#pragma unroll
    for (int kc = 0; kc < 8; ++kc) {
      short8 kf =
          *(const short8*)&Ksc[rk * 128 + (((kc * 2 + hi) ^ (rk & 7)) * 8)];
      s2 = MFMA32(kf, qf[kc], s2);
    }
    __builtin_amdgcn_s_setprio(0);

    // ---- softmax slice: lane-local exp2 (in-place) + mask + row-sum ----
    const bool diag = (kt >= 2 * qt);
#pragma unroll
    for (int r = 0; r < 16; ++r) {
      float e = exp2f(s2[r]);
      if (diag) {
        const int kcol = kt * 64 + wk * 32 + (r & 3) + 8 * (r >> 2) + 4 * hi;
        const int qrow = q0 + wr * 32 + l31;
        if (kcol > qrow) e = 0.f;
      }
      s2[r] = e;
      osum += e;
    }

    // ---- pack to PV A-fragments: cvt_pk + permlane32_swap (v2-verified) ----
    short8 pa2[2];
#pragma unroll
    for (int ks2 = 0; ks2 < 2; ++ks2) {
      uint32_t y0, y1, y2, y3;
      asm("v_cvt_pk_bf16_f32 %0, %1, %2"
          : "=v"(y0) : "v"(s2[ks2 * 8 + 0]), "v"(s2[ks2 * 8 + 1]));
      asm("v_cvt_pk_bf16_f32 %0, %1, %2"
          : "=v"(y1) : "v"(s2[ks2 * 8 + 2]), "v"(s2[ks2 * 8 + 3]));
      asm("v_cvt_pk_bf16_f32 %0, %1, %2"
          : "=v"(y2) : "v"(s2[ks2 * 8 + 4]), "v"(s2[ks2 * 8 + 5]));
      asm("v_cvt_pk_bf16_f32 %0, %1, %2"
          : "=v"(y3) : "v"(s2[ks2 * 8 + 6]), "v"(s2[ks2 * 8 + 7]));
      asm volatile("v_permlane32_swap_b32 %0, %1" : "+v"(y0), "+v"(y2));
      asm volatile("v_permlane32_swap_b32 %0, %1" : "+v"(y1), "+v"(y3));
      int4 t4;
      t4.x = (int)y0; t4.y = (int)y1; t4.z = (int)y2; t4.w = (int)y3;
      pa2[ks2] = *(short8*)&t4;
    }

    // ---- O += P V over this 32-k slice (d = full 128) ----
    __builtin_amdgcn_s_setprio(1);
#pragma unroll
    for (int ks2 = 0; ks2 < 2; ++ks2) {
#pragma unroll
      for (int dt = 0; dt < 4; ++dt) {
        const int rv = dt * 32 + l31;
        short8 vf = *(const short8*)&Vsc[rv * 64 +
                                         (((wk * 4 + ks2 * 2 + hi) ^ (rv & 7)) * 8)];
        o[dt] = MFMA32(pa2[ks2], vf, o[dt]);
      }
    }
    __builtin_amdgcn_s_setprio(0);
  }

  // ---- epilogue: combine wk pair's partial O/osum via LDS ----
  const float osum_full = osum + __shfl_xor(osum, 32);
  __syncthreads();  // all waves done reading K/V LDS; fex reuse safe
  if (wk == 1) {
#pragma unroll
    for (int dt = 0; dt < 4; ++dt)
#pragma unroll
      for (int r = 0; r < 16; ++r) {
        const int qr = wr * 32 + (r & 3) + 8 * (r >> 2) + 4 * hi;
        fex[qr * 128 + dt * 32 + l31] = o[dt][r];
      }
  }
  if (hi == 0) fex[16384 + wk * 128 + wr * 32 + l31] = osum_full;
  __syncthreads();
  if (wk == 0) {
#pragma unroll
    for (int r = 0; r < 16; ++r) {
      const int qr = wr * 32 + (r & 3) + 8 * (r >> 2) + 4 * hi;
      const float st = fex[16384 + qr] + fex[16384 + 128 + qr];
      const float inv = 1.f / st;
#pragma unroll
      for (int dt = 0; dt < 4; ++dt) {
        const float v = o[dt][r] + fex[qr * 128 + dt * 32 + l31];
        aout[(size_t)(b * T + q0 + qr) * D + h * 128 + dt * 32 + l31] =
            f2bf(v * inv);
      }
    }
  }
}

extern "C" void kernel_launch(void* const* d_in, const int* in_sizes, int n_in,
                              void* d_out, int out_size, void* d_ws, size_t ws_size,
                              hipStream_t stream) {
  const float* x = (const float*)d_in[0];
  // d_in[1] = causal mask; applied analytically (exactly equivalent)
  const float* w_qkv = (const float*)d_in[2];
  const float* w_out = (const float*)d_in[3];
  const float* b_out = (const float*)d_in[4];
  float* out = (float*)d_out;

  const int BT = 4096, D = 2048, D3 = 6144;
  u16* xb = (u16*)d_ws;                   // BT*D
  u16* wqkvb = xb + (size_t)BT * D;       // D3*D
  u16* woutb = wqkvb + (size_t)D3 * D;    // D*D
  u16* qkb = woutb + (size_t)D * D;       // BT*4096 (Q|K)
  u16* vtb = qkb + (size_t)BT * 4096;     // 2048*4096 (V^T as [h][d][b][t])
  u16* attnb = vtb + (size_t)D * BT;      // BT*D

  const int total8 = (BT * D + D3 * D + D * D) / 8;  // 3145728
  cvt_all<<<total8 / 256, 256, 0, stream>>>(x, w_qkv, w_out, xb, wqkvb, woutb);
  proj8_gemm<<<256, 512, 0, stream>>>(xb, wqkvb, qkb);
  vproj_gemm<<<512, 256, 0, stream>>>(wqkvb, xb, vtb);
  flash_attn<<<512, 512, 0, stream>>>(qkb, vtb, attnb);
  out_gemm<<<512, 256, 0, stream>>>(attnb, woutb, out, b_out);
}

// Round 11
// 340.130 us; speedup vs baseline: 1.0192x; 1.0192x over previous
//
#include <hip/hip_runtime.h>
#include <stdint.h>

typedef uint16_t u16;
typedef __attribute__((ext_vector_type(8))) short short8;
typedef __attribute__((ext_vector_type(4))) float f32x4;
typedef __attribute__((ext_vector_type(16))) float f32x16;

#define MFMA16(a, b, c) __builtin_amdgcn_mfma_f32_16x16x32_bf16((a), (b), (c), 0, 0, 0)
#define MFMA32(a, b, c) __builtin_amdgcn_mfma_f32_32x32x16_bf16((a), (b), (c), 0, 0, 0)
#define AS1 __attribute__((address_space(1)))
#define AS3 __attribute__((address_space(3)))

__device__ __forceinline__ void gld_lds16(const u16* g, u16* l) {
  __builtin_amdgcn_global_load_lds((const AS1 void*)g, (AS3 void*)l, 16, 0, 0);
}

__device__ __forceinline__ u16 f2bf(float f) {
  uint32_t u = __float_as_uint(f);
  u += 0x7fffu + ((u >> 16) & 1u);
  return (u16)(u >> 16);
}

// ---------------- fused fp32 -> bf16, 32B/thread (x, w_qkv, w_out) ----------
__global__ __launch_bounds__(256) void cvt_all(const float* __restrict__ x,
                                               const float* __restrict__ wqkv,
                                               const float* __restrict__ wout,
                                               u16* __restrict__ xb,
                                               u16* __restrict__ wqkvb,
                                               u16* __restrict__ woutb) {
  const int n1 = 8388608 / 8, n2 = 12582912 / 8;  // x, w_qkv float8 counts
  int i = blockIdx.x * 256 + threadIdx.x;
  const float* src;
  u16* dst;
  int j;
  if (i < n1) {
    src = x; dst = xb; j = i;
  } else if (i < n1 + n2) {
    src = wqkv; dst = wqkvb; j = i - n1;
  } else {
    src = wout; dst = woutb; j = i - n1 - n2;
  }
  float4 v0 = ((const float4*)src)[j * 2];
  float4 v1 = ((const float4*)src)[j * 2 + 1];
  uint4 o;
  o.x = (uint32_t)f2bf(v0.x) | ((uint32_t)f2bf(v0.y) << 16);
  o.y = (uint32_t)f2bf(v0.z) | ((uint32_t)f2bf(v0.w) << 16);
  o.z = (uint32_t)f2bf(v1.x) | ((uint32_t)f2bf(v1.y) << 16);
  o.w = (uint32_t)f2bf(v1.z) | ((uint32_t)f2bf(v1.w) << 16);
  ((uint4*)dst)[j] = o;
}

// ---------------- barriers ---------------------------------------------------
template <int N>
__device__ __forceinline__ void bar_vm() {  // asm-fenced: pins memory-op order
  asm volatile("s_waitcnt vmcnt(%0)\n\ts_barrier" ::"n"(N) : "memory");
}
__device__ __forceinline__ void bar_fence() {
  asm volatile("s_barrier" ::: "memory");
}

// ============================================================================
// 256x256 GEMM (QK-proj), R11: MINIMAL-FENCE loop.
// R10 post-mortem: MFMA (~2480cyc) and ds_read (~2300cyc) per K-tile each sat
// at ~45% because every barrier was an asm "memory" fence -- the compiler
// could not pipeline any ds_read under any MFMA.  R11 keeps exactly TWO sync
// points per tile and lets q1-q3 free-flow:
//   q0:  stage group_A(t)={Ae,Ao(t+1)};  read bf[8]+af0;  MFMA(af0)
//        sched_barrier(0); fenced s_barrier   <- pins q0 MFMAs+lgkm waits:
//        all bf reads COMPLETE before any wave passes (WAR for group_B)
//   q1:  stage group_B(t)={B0,B1(t+2)} (writes CURRENT B slot - safe, bf done)
//        read af1; MFMA(af1)
//   q2:  read af2; MFMA(af2)        (no barriers: reads pipeline under MFMA)
//   q3:  read af3; MFMA(af3);  bar_vm<4>
// Reorder-robust ledger (each group alone in its asm-fence window, so intra-
// window reordering cannot change vmcnt semantics):
//   at t q3-end: outstanding = group_B(t-1)[4] + group_A(t)[4] + group_B(t)[4]
//   vmcnt(4) forces group_B(t-1) (=B(t+1)) and group_A(t) (=A(t+1)); keeps
//   group_B(t) (=B(t+2)) flying.  Tails: t=NT-2 vmcnt(0); t=NT-1 none.
// Prologue: stage B(0),A(0),B(1); one-time vmcnt(0) drain.
// Swizzle: physical chunk pc holds global chunk pc^(r&7) (R2-proven, 0 cfl).
// Q columns (nt<8) pre-scaled by HD^-0.5*log2(e) so flash softmax = exp2(S).
// ============================================================================
__global__ __launch_bounds__(512, 2) void proj8_gemm(const u16* __restrict__ xb,
                                                     const u16* __restrict__ wqkvb,
                                                     u16* __restrict__ qkb) {
  constexpr int ASZ = 256 * 64;  // u16 per slot
  constexpr int NT = 32;         // 2048 / BK=64
  __shared__ u16 sm[4 * ASZ];    // [A0][A1][B0][B1] = 128 KiB

  int bx = blockIdx.x;
  bx = (bx & 7) * 32 + (bx >> 3);  // 256 = 8 XCD chunks of 32
  const int mt = bx >> 4, nt = bx & 15;
  const u16* Ab = xb + (size_t)mt * 256 * 2048;
  const u16* Bb = wqkvb + (size_t)nt * 256 * 2048;
  u16* C = qkb + (size_t)mt * 256 * 4096 + nt * 256;

  const int tid = threadIdx.x, lane = tid & 63, w = tid >> 6;
  const int wm = w >> 2, wn = w & 3;
  const int lo = lane & 15, q4 = lane >> 4;

  f32x4 acc[8][4];
  const f32x4 fzero = {0.f, 0.f, 0.f, 0.f};
#pragma unroll
  for (int i = 0; i < 8; ++i)
#pragma unroll
    for (int j = 0; j < 4; ++j) acc[i][j] = fzero;

  // stage one 16 KiB half of K-tile tau.  h: 0=B rows 0-127, 1=B rows 128-255,
  // 2=A rows {0-63,128-191} (Ae), 3=A rows {64-127,192-255} (Ao).
  auto stage_half = [&](int tau, int h) {
    const int slot = tau & 1;
    const int k0 = tau * 64;
    const u16* G = (h < 2) ? Bb : Ab;
    u16* L = sm + (h < 2 ? 2 * ASZ : 0) + slot * ASZ;
#pragma unroll
    for (int s = 0; s < 2; ++s) {
      const int c = tid + s * 512;        // 0..1023 chunk-in-half
      const int hr = c >> 3, pc = c & 7;  // hr 0..127
      const int r = (h < 2) ? (h * 128 + hr)
                            : ((hr & 63) + ((hr >> 6) << 7) + ((h & 1) << 6));
      const int c4 = pc ^ (r & 7);  // pre-swizzled global chunk
      gld_lds16(G + (size_t)r * 2048 + k0 + c4 * 8, L + r * 64 + pc * 8);
    }
  };

  // prologue: tile 0 fully + B halves of tile 1; one-time full drain
  stage_half(0, 0);
  stage_half(0, 1);
  stage_half(0, 2);
  stage_half(0, 3);
  stage_half(1, 0);
  stage_half(1, 1);
  bar_vm<0>();

  for (int tau = 0; tau < NT; ++tau) {
    const u16* As = sm + (tau & 1) * ASZ;
    const u16* Bs = sm + 2 * ASZ + (tau & 1) * ASZ;

    // ---- q0: group_A stage, bf + af0 reads, MFMA quadrant 0 ----
    if (tau + 1 < NT) {
      stage_half(tau + 1, 2);
      stage_half(tau + 1, 3);
    }
    short8 bf[8];
#pragma unroll
    for (int j = 0; j < 4; ++j)
#pragma unroll
      for (int kk = 0; kk < 2; ++kk) {
        const int r = wn * 64 + j * 16 + lo;
        bf[j * 2 + kk] =
            *(const short8*)(Bs + r * 64 + (((kk * 4 + q4) ^ (r & 7)) * 8));
      }
    {
      short8 af[2][2];
#pragma unroll
      for (int i = 0; i < 2; ++i)
#pragma unroll
        for (int kk = 0; kk < 2; ++kk) {
          const int r = wm * 128 + 0 * 32 + i * 16 + lo;
          af[i][kk] =
              *(const short8*)(As + r * 64 + (((kk * 4 + q4) ^ (r & 7)) * 8));
        }
      __builtin_amdgcn_s_setprio(1);
#pragma unroll
      for (int i = 0; i < 2; ++i)
#pragma unroll
        for (int j = 0; j < 4; ++j)
#pragma unroll
          for (int kk = 0; kk < 2; ++kk)
            acc[i][j] = MFMA16(af[i][kk], bf[j * 2 + kk], acc[i][j]);
      __builtin_amdgcn_s_setprio(0);
    }
    __builtin_amdgcn_sched_barrier(0);  // pin q0 MFMAs (and their lgkm waits)
    bar_fence();                        // q0-end: bf reads complete block-wide

    // ---- q1: group_B stage (current B slot now safe), af1, MFMA q1 ----
    if (tau + 2 < NT) {
      stage_half(tau + 2, 0);
      stage_half(tau + 2, 1);
    }
#pragma unroll
    for (int q = 1; q < 4; ++q) {  // q1..q3 free-flow: reads pipeline w/ MFMA
      short8 af[2][2];
#pragma unroll
      for (int i = 0; i < 2; ++i)
#pragma unroll
        for (int kk = 0; kk < 2; ++kk) {
          const int r = wm * 128 + q * 32 + i * 16 + lo;
          af[i][kk] =
              *(const short8*)(As + r * 64 + (((kk * 4 + q4) ^ (r & 7)) * 8));
        }
      __builtin_amdgcn_s_setprio(1);
#pragma unroll
      for (int i = 0; i < 2; ++i)
#pragma unroll
        for (int j = 0; j < 4; ++j)
#pragma unroll
          for (int kk = 0; kk < 2; ++kk)
            acc[q * 2 + i][j] = MFMA16(af[i][kk], bf[j * 2 + kk], acc[q * 2 + i][j]);
      __builtin_amdgcn_s_setprio(0);
    }

    // ---- q3-end: counted-vmcnt barrier (ledger above) ----
    if (tau + 2 < NT) {
      bar_vm<4>();
    } else if (tau + 1 < NT) {
      bar_vm<0>();  // tau = NT-2: nothing newer to keep
    }                // tau = NT-1: exit
  }

  // epilogue: per-wave 128x64 at (wm*128, wn*64); scale Q (nt<8) by cexp
  const float sc =
      (nt < 8) ? (0.08838834764831843f * 1.4426950408889634f) : 1.0f;
#pragma unroll
  for (int i = 0; i < 8; ++i)
#pragma unroll
    for (int j = 0; j < 4; ++j) {
      const int col = wn * 64 + j * 16 + lo;
#pragma unroll
      for (int e = 0; e < 4; ++e) {
        const int row = wm * 128 + i * 16 + q4 * 4 + e;
        C[(size_t)row * 4096 + col] = f2bf(acc[i][j][e] * sc);
      }
    }
}

// ---------------- GEMM core: cyclic-3, counted vmcnt, superrow swizzle ------
// (R2-verified, 0 bank conflicts.)  C[BM,128] += A[BM,K]*B[128,K]^T, BK=32.
template <int MFR>  // 8 => BM=256, 4 => BM=128
__device__ __forceinline__ void gemm_core3(const u16* __restrict__ Ab,
                                           const u16* __restrict__ Bb,
                                           u16* sm, int tid,
                                           f32x4 acc[MFR][4]) {
  constexpr int AROWS = MFR * 32;
  constexpr int ASZ = AROWS * 32;
  constexpr int BSZ = 128 * 32;
  constexpr int BUF = ASZ + BSZ;
  constexpr int NT = 64;
  constexpr int ALD = AROWS / 64;
  constexpr int VN = ALD + 2;

  const int lane = tid & 63, w = tid >> 6;
  const int wr = w >> 1, wc = w & 1;
  const int lo = lane & 15, q4 = lane >> 4;
  const int pcl = (((lo & 1) << 2) | q4) ^ ((lo >> 1) & 7);
  const int loff = (lo >> 1) * 64 + pcl * 8;

  auto stage = [&](int g) {
    u16* As = sm + (g % 3) * BUF;
    u16* Bs = As + ASZ;
    const int k0 = g * 32;
#pragma unroll
    for (int s = 0; s < ALD; ++s) {
      const int c = tid + s * 256;
      const int sr = c >> 3, pc = c & 7;
      const int t = pc ^ (sr & 7);
      const int r = sr * 2 + (t >> 2), c4 = t & 3;
      gld_lds16(Ab + (size_t)r * 2048 + k0 + c4 * 8, As + c * 8);
    }
#pragma unroll
    for (int s = 0; s < 2; ++s) {
      const int c = tid + s * 256;
      const int sr = c >> 3, pc = c & 7;
      const int t = pc ^ (sr & 7);
      const int r = sr * 2 + (t >> 2), c4 = t & 3;
      gld_lds16(Bb + (size_t)r * 2048 + k0 + c4 * 8, Bs + c * 8);
    }
  };

  stage(0);
  stage(1);
  bar_vm<VN>();

  for (int g = 0; g < NT; ++g) {
    const u16* As = sm + (g % 3) * BUF;
    const u16* Bs = As + ASZ;
    if (g + 2 < NT) stage(g + 2);
    short8 af[MFR], bf[4];
#pragma unroll
    for (int i = 0; i < MFR; ++i)
      af[i] = *(const short8*)(As + (wr * (MFR * 16) + i * 16) * 32 + loff);
#pragma unroll
    for (int j = 0; j < 4; ++j)
      bf[j] = *(const short8*)(Bs + (wc * 64 + j * 16) * 32 + loff);
    __builtin_amdgcn_s_setprio(1);
#pragma unroll
    for (int i = 0; i < MFR; ++i)
#pragma unroll
      for (int j = 0; j < 4; ++j) acc[i][j] = MFMA16(af[i], bf[j], acc[i][j]);
    __builtin_amdgcn_s_setprio(0);
    if (g + 1 < NT) {
      if (g + 2 < NT) {
        bar_vm<VN>();
      } else {
        bar_vm<0>();
      }
    }
  }
}

// ---------------- V^T projection: vt[d, b*t] = Wv * x^T ----------------
// 512 blocks of 128x128 (MFR=4), 48 KiB -> 2 blocks/CU, one full round.
__global__ __launch_bounds__(256, 2) void vproj_gemm(const u16* __restrict__ wqkvb,
                                                     const u16* __restrict__ xb,
                                                     u16* __restrict__ vtb) {
  __shared__ u16 sm[3 * (128 * 32 + 128 * 32)];  // 48 KiB
  int bx = blockIdx.x;
  bx = (bx & 7) * 64 + (bx >> 3);  // 512 = 8 XCD chunks of 64
  const int tid = threadIdx.x;
  const int mt = bx >> 5, nt = bx & 31;  // M=2048/128=16, N=4096/128=32
  const u16* Ab = wqkvb + (size_t)(4096 + mt * 128) * 2048;
  const u16* Bb = xb + (size_t)nt * 128 * 2048;
  u16* C = vtb + (size_t)mt * 128 * 4096 + nt * 128;
  f32x4 acc[4][4];
  const f32x4 fzero = {0.f, 0.f, 0.f, 0.f};
#pragma unroll
  for (int i = 0; i < 4; ++i)
#pragma unroll
    for (int j = 0; j < 4; ++j) acc[i][j] = fzero;

  gemm_core3<4>(Ab, Bb, sm, tid, acc);

  const int lane = tid & 63, w = tid >> 6;
  const int wr = w >> 1, wc = w & 1;
  const int lo = lane & 15, q4 = lane >> 4;
#pragma unroll
  for (int i = 0; i < 4; ++i)
#pragma unroll
    for (int j = 0; j < 4; ++j) {
      const int col = wc * 64 + j * 16 + lo;
#pragma unroll
      for (int e = 0; e < 4; ++e) {
        const int row = wr * 64 + i * 16 + q4 * 4 + e;
        C[(size_t)row * 4096 + col] = f2bf(acc[i][j][e]);
      }
    }
}

// ---------------- out-proj GEMM: out = attn * Wout^T + bias (f32) ----------
// 512 blocks of 128x128 (MFR=4), 48 KiB -> 2 blocks/CU, one full round.
__global__ __launch_bounds__(256, 2) void out_gemm(const u16* __restrict__ A,
                                                   const u16* __restrict__ B,
                                                   float* __restrict__ Cf,
                                                   const float* __restrict__ bias) {
  __shared__ u16 sm[3 * (128 * 32 + 128 * 32)];  // 48 KiB
  int bx = blockIdx.x;
  bx = (bx & 7) * 64 + (bx >> 3);  // 512 = 8 XCD chunks of 64
  const int tid = threadIdx.x;
  const int mt = bx >> 4, nt = bx & 15;  // M=4096/128=32, N=2048/128=16
  const u16* Ab = A + (size_t)mt * 128 * 2048;
  const u16* Bb = B + (size_t)nt * 128 * 2048;
  f32x4 acc[4][4];
  const f32x4 fzero = {0.f, 0.f, 0.f, 0.f};
#pragma unroll
  for (int i = 0; i < 4; ++i)
#pragma unroll
    for (int j = 0; j < 4; ++j) acc[i][j] = fzero;

  gemm_core3<4>(Ab, Bb, sm, tid, acc);

  const int lane = tid & 63, w = tid >> 6;
  const int wr = w >> 1, wc = w & 1;
  const int lo = lane & 15, q4 = lane >> 4;
#pragma unroll
  for (int i = 0; i < 4; ++i)
#pragma unroll
    for (int j = 0; j < 4; ++j) {
      const int col = nt * 128 + wc * 64 + j * 16 + lo;
      const float bv = bias[col];
#pragma unroll
      for (int e = 0; e < 4; ++e) {
        const int row = mt * 128 + wr * 64 + i * 16 + q4 * 4 + e;
        Cf[(size_t)row * 2048 + col] = acc[i][j][e] + bv;
      }
    }
}

// ---------------- flash attention v4: KVBLK=64, 2 blocks/CU ------------------
// (R8-verified: swapped QK^T, in-register softmax, cvt_pk+permlane pack,
// anti-paired q-tile grid, no VGPR cap; R9: setprio around MFMA clusters.)
__global__ __launch_bounds__(512) void flash_attn(const u16* __restrict__ qk,
                                                  const u16* __restrict__ vt,
                                                  u16* __restrict__ aout) {
  constexpr int T = 2048, WQK = 4096, D = 2048;
  constexpr int KT = 64 * 128;        // u16 per tile (K [64][128], V [128][64])
  __shared__ u16 smem[4 * KT + 512];  // 64 KiB KV (+1 KiB osum; epi reuse)

  const int bx = blockIdx.x;
  const int g = bx & 31;
  const int h = g & 15, b = g >> 4;
  const int qt = (bx < 256) ? (bx >> 5) : (15 - ((bx - 256) >> 5));
  const int q0 = qt * 128;
  const int tid = threadIdx.x, lane = tid & 63, w = tid >> 6;
  const int wr = w & 3, wk = w >> 2;  // 4 q-groups x 2 k-halves
  const int l31 = lane & 31, hi = lane >> 5;

  const u16* Qb = qk + (size_t)b * T * WQK + h * 128;
  const u16* Kb = Qb + 2048;
  const u16* Vtb = vt + (size_t)h * 128 * 4096 + b * 2048;
  float* fex = (float*)smem;  // epilogue scratch: [128][128] f32 + 2x128 osum

  // Q frags (B-operand): rows q0+wr*32+l31, k = kc*16+hi*8+j (pre-scaled)
  short8 qf[8];
#pragma unroll
  for (int kc = 0; kc < 8; ++kc)
    qf[kc] = *(const short8*)(Qb + (size_t)(q0 + wr * 32 + l31) * WQK +
                              kc * 16 + hi * 8);

  f32x16 o[4];
  float osum = 0.f;
#pragma unroll
  for (int dt = 0; dt < 4; ++dt)
#pragma unroll
    for (int e = 0; e < 16; ++e) o[dt][e] = 0.f;

  auto stage = [&](int kt) {
    const int kv0 = kt * 64;
    u16* Kl = smem + (kt & 1) * KT;
    u16* Vl = smem + 2 * KT + (kt & 1) * KT;
#pragma unroll
    for (int s = 0; s < 2; ++s) {
      const int c = tid + s * 512;
      {  // K: 64 rows x 16 chunks of 16B
        const int r = c >> 4, pc = c & 15;
        const int gc = pc ^ (r & 7);
        gld_lds16(Kb + (size_t)(kv0 + r) * WQK + gc * 8, Kl + c * 8);
      }
      {  // V: 128 rows x 8 chunks of 16B
        const int r = c >> 3, pc = c & 7;
        const int gc = pc ^ (r & 7);
        gld_lds16(Vtb + (size_t)r * 4096 + kv0 + gc * 8, Vl + c * 8);
      }
    }
  };

  stage(0);
  const int ktmax = 2 * qt + 1;
  for (int kt = 0; kt <= ktmax; ++kt) {
    __syncthreads();  // cur tiles landed; prev tiles' reads done
    if (kt < ktmax) stage(kt + 1);
    const u16* Ksc = smem + (kt & 1) * KT;
    const u16* Vsc = smem + 2 * KT + (kt & 1) * KT;

    // ---- S^T = K Q^T over this wave's 32-k half ----
    f32x16 s2;
#pragma unroll
    for (int e = 0; e < 16; ++e) s2[e] = 0.f;
    const int rk = wk * 32 + l31;
    __builtin_amdgcn_s_setprio(1);
#pragma unroll
    for (int kc = 0; kc < 8; ++kc) {
      short8 kf =
          *(const short8*)&Ksc[rk * 128 + (((kc * 2 + hi) ^ (rk & 7)) * 8)];
      s2 = MFMA32(kf, qf[kc], s2);
    }
    __builtin_amdgcn_s_setprio(0);

    // ---- softmax slice: lane-local exp2 (in-place) + mask + row-sum ----
    const bool diag = (kt >= 2 * qt);
#pragma unroll
    for (int r = 0; r < 16; ++r) {
      float e = exp2f(s2[r]);
      if (diag) {
        const int kcol = kt * 64 + wk * 32 + (r & 3) + 8 * (r >> 2) + 4 * hi;
        const int qrow = q0 + wr * 32 + l31;
        if (kcol > qrow) e = 0.f;
      }
      s2[r] = e;
      osum += e;
    }

    // ---- pack to PV A-fragments: cvt_pk + permlane32_swap (v2-verified) ----
    short8 pa2[2];
#pragma unroll
    for (int ks2 = 0; ks2 < 2; ++ks2) {
      uint32_t y0, y1, y2, y3;
      asm("v_cvt_pk_bf16_f32 %0, %1, %2"
          : "=v"(y0) : "v"(s2[ks2 * 8 + 0]), "v"(s2[ks2 * 8 + 1]));
      asm("v_cvt_pk_bf16_f32 %0, %1, %2"
          : "=v"(y1) : "v"(s2[ks2 * 8 + 2]), "v"(s2[ks2 * 8 + 3]));
      asm("v_cvt_pk_bf16_f32 %0, %1, %2"
          : "=v"(y2) : "v"(s2[ks2 * 8 + 4]), "v"(s2[ks2 * 8 + 5]));
      asm("v_cvt_pk_bf16_f32 %0, %1, %2"
          : "=v"(y3) : "v"(s2[ks2 * 8 + 6]), "v"(s2[ks2 * 8 + 7]));
      asm volatile("v_permlane32_swap_b32 %0, %1" : "+v"(y0), "+v"(y2));
      asm volatile("v_permlane32_swap_b32 %0, %1" : "+v"(y1), "+v"(y3));
      int4 t4;
      t4.x = (int)y0; t4.y = (int)y1; t4.z = (int)y2; t4.w = (int)y3;
      pa2[ks2] = *(short8*)&t4;
    }

    // ---- O += P V over this 32-k slice (d = full 128) ----
    __builtin_amdgcn_s_setprio(1);
#pragma unroll
    for (int ks2 = 0; ks2 < 2; ++ks2) {
#pragma unroll
      for (int dt = 0; dt < 4; ++dt) {
        const int rv = dt * 32 + l31;
        short8 vf = *(const short8*)&Vsc[rv * 64 +
                                         (((wk * 4 + ks2 * 2 + hi) ^ (rv & 7)) * 8)];
        o[dt] = MFMA32(pa2[ks2], vf, o[dt]);
      }
    }
    __builtin_amdgcn_s_setprio(0);
  }

  // ---- epilogue: combine wk pair's partial O/osum via LDS ----
  const float osum_full = osum + __shfl_xor(osum, 32);
  __syncthreads();  // all waves done reading K/V LDS; fex reuse safe
  if (wk == 1) {
#pragma unroll
    for (int dt = 0; dt < 4; ++dt)
#pragma unroll
      for (int r = 0; r < 16; ++r) {
        const int qr = wr * 32 + (r & 3) + 8 * (r >> 2) + 4 * hi;
        fex[qr * 128 + dt * 32 + l31] = o[dt][r];
      }
  }
  if (hi == 0) fex[16384 + wk * 128 + wr * 32 + l31] = osum_full;
  __syncthreads();
  if (wk == 0) {
#pragma unroll
    for (int r = 0; r < 16; ++r) {
      const int qr = wr * 32 + (r & 3) + 8 * (r >> 2) + 4 * hi;
      const float st = fex[16384 + qr] + fex[16384 + 128 + qr];
      const float inv = 1.f / st;
#pragma unroll
      for (int dt = 0; dt < 4; ++dt) {
        const float v = o[dt][r] + fex[qr * 128 + dt * 32 + l31];
        aout[(size_t)(b * T + q0 + qr) * D + h * 128 + dt * 32 + l31] =
            f2bf(v * inv);
      }
    }
  }
}

extern "C" void kernel_launch(void* const* d_in, const int* in_sizes, int n_in,
                              void* d_out, int out_size, void* d_ws, size_t ws_size,
                              hipStream_t stream) {
  const float* x = (const float*)d_in[0];
  // d_in[1] = causal mask; applied analytically (exactly equivalent)
  const float* w_qkv = (const float*)d_in[2];
  const float* w_out = (const float*)d_in[3];
  const float* b_out = (const float*)d_in[4];
  float* out = (float*)d_out;

  const int BT = 4096, D = 2048, D3 = 6144;
  u16* xb = (u16*)d_ws;                   // BT*D
  u16* wqkvb = xb + (size_t)BT * D;       // D3*D
  u16* woutb = wqkvb + (size_t)D3 * D;    // D*D
  u16* qkb = woutb + (size_t)D * D;       // BT*4096 (Q|K)
  u16* vtb = qkb + (size_t)BT * 4096;     // 2048*4096 (V^T as [h][d][b][t])
  u16* attnb = vtb + (size_t)D * BT;      // BT*D

  const int total8 = (BT * D + D3 * D + D * D) / 8;  // 3145728
  cvt_all<<<total8 / 256, 256, 0, stream>>>(x, w_qkv, w_out, xb, wqkvb, woutb);
  proj8_gemm<<<256, 512, 0, stream>>>(xb, wqkvb, qkb);
  vproj_gemm<<<512, 256, 0, stream>>>(wqkvb, xb, vtb);
  flash_attn<<<512, 512, 0, stream>>>(qkb, vtb, attnb);
  out_gemm<<<512, 256, 0, stream>>>(attnb, woutb, out, b_out);
}